// Round 1
// baseline (227.980 us; speedup 1.0000x reference)
//
#include <hip/hip_runtime.h>

#define LLEN 8192
#define CG 16
#define NG 512   // b(16) * GROUPS(32)

// ---------------- Pass 1: per-row sums. One wave (64 lanes) per row. ----------------
__global__ __launch_bounds__(256) void rowsum_kernel(const float* __restrict__ x,
                                                     float* __restrict__ S) {
    int wave = (blockIdx.x * 256 + threadIdx.x) >> 6;   // row id, 0..8191
    int lane = threadIdx.x & 63;
    if (wave >= NG * CG) return;
    const float4* xr = reinterpret_cast<const float4*>(x + (size_t)wave * LLEN);
    float s = 0.f;
    #pragma unroll
    for (int k = 0; k < 32; ++k) {
        float4 v = xr[k * 64 + lane];
        s += (v.x + v.y) + (v.z + v.w);
    }
    #pragma unroll
    for (int off = 32; off > 0; off >>= 1)
        s += __shfl_down(s, off, 64);
    if (lane == 0) S[wave] = s;
}

// ---------------- Pass 2: per-group softmax weights -> v0,v1,v2,c ----------------
__global__ __launch_bounds__(256) void prep_kernel(const float* __restrict__ x,
                                                   const float* __restrict__ S,
                                                   const float* __restrict__ w1,
                                                   const float* __restrict__ b1,
                                                   const float* __restrict__ w3,
                                                   const float* __restrict__ b3,
                                                   float* __restrict__ vw) {
    int g = blockIdx.x * 256 + threadIdx.x;
    if (g >= NG) return;
    float Sg[CG], first[CG], last[CG];
    #pragma unroll
    for (int i = 0; i < CG; ++i) {
        int row = g * CG + i;
        Sg[i]    = S[row];
        first[i] = x[(size_t)row * LLEN];
        last[i]  = x[(size_t)row * LLEN + (LLEN - 1)];
    }
    const float invL = 1.0f / (float)LLEN;
    float m1[CG], m2[CG];
    #pragma unroll
    for (int o = 0; o < CG; ++o) {
        float s1 = 0.f, s2 = 0.f;
        #pragma unroll
        for (int i = 0; i < CG; ++i) {
            s1 += w1[o * CG + i] * Sg[i];
            const float* w = &w3[(o * CG + i) * 3];
            s2 += w[0] * (Sg[i] - last[i]) + w[1] * Sg[i] + w[2] * (Sg[i] - first[i]);
        }
        m1[o] = s1 * invL + b1[o];
        m2[o] = s2 * invL + b3[o];
    }
    // softmax over the 16 channels (both heads)
    float mx1 = -1e30f, mx2 = -1e30f;
    #pragma unroll
    for (int o = 0; o < CG; ++o) { mx1 = fmaxf(mx1, m1[o]); mx2 = fmaxf(mx2, m2[o]); }
    float d1 = 0.f, d2 = 0.f;
    #pragma unroll
    for (int o = 0; o < CG; ++o) {
        m1[o] = __expf(m1[o] - mx1); d1 += m1[o];
        m2[o] = __expf(m2[o] - mx2); d2 += m2[o];
    }
    float r1 = 1.f / d1, r2 = 1.f / d2;
    #pragma unroll
    for (int o = 0; o < CG; ++o) { m1[o] *= r1; m2[o] *= r2; }   // now a1, a2
    float cbias = 0.f;
    #pragma unroll
    for (int o = 0; o < CG; ++o) cbias += m1[o] * b3[o] + m2[o] * b1[o];
    float* outv = &vw[g * 64];
    #pragma unroll
    for (int i = 0; i < CG; ++i) {
        float v0 = 0.f, v1 = 0.f, v2 = 0.f;
        #pragma unroll
        for (int o = 0; o < CG; ++o) {
            const float a1o = m1[o], a2o = m2[o];
            const float* w = &w3[(o * CG + i) * 3];
            v0 += a1o * w[0];
            v1 += a1o * w[1] + a2o * w1[o * CG + i];
            v2 += a1o * w[2];
        }
        outv[i]      = v0;
        outv[16 + i] = v1;
        outv[32 + i] = v2;
    }
    outv[48] = cbias;
}

// ---------------- Pass 3: weights -> sigmoid gate -> output ----------------
// One wave handles one (group, 256-column chunk). Lane t owns columns 4t..4t+3.
__global__ __launch_bounds__(256) void apply_kernel(const float* __restrict__ x,
                                                    const float* __restrict__ vw,
                                                    float* __restrict__ out) {
    int wave = (blockIdx.x * 256 + threadIdx.x) >> 6;   // 0..16383
    int lane = threadIdx.x & 63;
    int g  = wave >> 5;             // 32 chunks per group
    int c0 = (wave & 31) * 256;
    const float* vp = &vw[g * 64];

    const float cb = vp[48];
    float w0 = cb, w1a = cb, w2a = cb, w3a = cb;
    float4 xv[CG];
    #pragma unroll
    for (int i = 0; i < CG; ++i) {
        size_t rb = ((size_t)(g * CG + i)) * LLEN + c0;
        float4 v = *reinterpret_cast<const float4*>(x + rb + 4 * lane);
        xv[i] = v;
        float le = 0.f, re = 0.f;
        if (c0 > 0)            le = x[rb - 1];          // uniform addr -> scalar load
        if (c0 + 256 < LLEN)   re = x[rb + 256];
        float fl = __shfl_up(v.w, 1, 64);
        if (lane == 0)  fl = le;
        float fr = __shfl_down(v.x, 1, 64);
        if (lane == 63) fr = re;
        const float a0 = vp[i], a1 = vp[16 + i], a2 = vp[32 + i];
        w0  += a0 * fl  + a1 * v.x + a2 * v.y;
        w1a += a0 * v.x + a1 * v.y + a2 * v.z;
        w2a += a0 * v.y + a1 * v.z + a2 * v.w;
        w3a += a0 * v.z + a1 * v.w + a2 * fr;
    }
    const float s0 = 1.f / (1.f + __expf(-w0));
    const float s1 = 1.f / (1.f + __expf(-w1a));
    const float s2 = 1.f / (1.f + __expf(-w2a));
    const float s3 = 1.f / (1.f + __expf(-w3a));
    #pragma unroll
    for (int i = 0; i < CG; ++i) {
        size_t rb = ((size_t)(g * CG + i)) * LLEN + c0 + 4 * lane;
        float4 v = xv[i];
        float4 o4 = make_float4(v.x * s0, v.y * s1, v.z * s2, v.w * s3);
        *reinterpret_cast<float4*>(out + rb) = o4;
    }
}

extern "C" void kernel_launch(void* const* d_in, const int* in_sizes, int n_in,
                              void* d_out, int out_size, void* d_ws, size_t ws_size,
                              hipStream_t stream) {
    const float* x  = (const float*)d_in[0];
    const float* w1 = (const float*)d_in[1];
    const float* b1 = (const float*)d_in[2];
    const float* w3 = (const float*)d_in[3];
    const float* b3 = (const float*)d_in[4];
    float* out = (float*)d_out;
    float* S   = (float*)d_ws;              // 8192 floats
    float* vw  = S + NG * CG;               // 512 * 64 floats

    // Pass 1: 8192 rows, 4 waves/block -> 2048 blocks
    rowsum_kernel<<<2048, 256, 0, stream>>>(x, S);
    // Pass 2: 512 groups, 1 thread each
    prep_kernel<<<2, 256, 0, stream>>>(x, S, w1, b1, w3, b3, vw);
    // Pass 3: 512 groups * 32 chunks = 16384 waves / 4 per block = 4096 blocks
    apply_kernel<<<4096, 256, 0, stream>>>(x, vw, out);
}

// Round 2
// 179.413 us; speedup vs baseline: 1.2707x; 1.2707x over previous
//
#include <hip/hip_runtime.h>

#define LLEN 8192
#define CG 16
#define NG 512   // b(16) * GROUPS(32)

// ---------------- Pass 1: per-row sums. One wave (64 lanes) per row. ----------------
__global__ __launch_bounds__(256) void rowsum_kernel(const float* __restrict__ x,
                                                     float* __restrict__ S) {
    int wave = (blockIdx.x * 256 + threadIdx.x) >> 6;   // row id, 0..8191
    int lane = threadIdx.x & 63;
    if (wave >= NG * CG) return;
    const float4* xr = reinterpret_cast<const float4*>(x + (size_t)wave * LLEN);
    float s = 0.f;
    #pragma unroll
    for (int k = 0; k < 32; ++k) {
        float4 v = xr[k * 64 + lane];
        s += (v.x + v.y) + (v.z + v.w);
    }
    #pragma unroll
    for (int off = 32; off > 0; off >>= 1)
        s += __shfl_down(s, off, 64);
    if (lane == 0) S[wave] = s;
}

// ---------------- Pass 2: per-group softmax weights -> v0,v1,v2,c ----------------
// One WAVE per group; lanes 0..15 each own a channel. 128 blocks x 4 waves = 512 groups.
__global__ __launch_bounds__(256) void prep_kernel(const float* __restrict__ x,
                                                   const float* __restrict__ S,
                                                   const float* __restrict__ w1,
                                                   const float* __restrict__ b1,
                                                   const float* __restrict__ w3,
                                                   const float* __restrict__ b3,
                                                   float* __restrict__ vw) {
    int wave = threadIdx.x >> 6;
    int lane = threadIdx.x & 63;
    int g = blockIdx.x * 4 + wave;          // 0..511
    int i = lane & 15;                      // channel index (lanes 16..63 duplicate)
    int row = g * CG + i;
    float sown = S[row];
    float fown = x[(size_t)row * LLEN];
    float lown = x[(size_t)row * LLEN + (LLEN - 1)];
    const float invL = 1.0f / (float)LLEN;

    // m1[o], m2[o] for o = i  (sum over k via width-16 broadcasts)
    float s1 = 0.f, s2 = 0.f;
    #pragma unroll
    for (int k = 0; k < CG; ++k) {
        float Sk = __shfl(sown, k, 16);
        float Fk = __shfl(fown, k, 16);
        float Lk = __shfl(lown, k, 16);
        s1 += w1[i * CG + k] * Sk;
        const float* w = &w3[(i * CG + k) * 3];
        s2 += w[0] * (Sk - Lk) + w[1] * Sk + w[2] * (Sk - Fk);
    }
    float m1 = s1 * invL + b1[i];
    float m2 = s2 * invL + b3[i];

    // softmax across the 16 lanes (both heads)
    float mx1 = m1, mx2 = m2;
    #pragma unroll
    for (int off = 8; off; off >>= 1) {
        mx1 = fmaxf(mx1, __shfl_xor(mx1, off, 16));
        mx2 = fmaxf(mx2, __shfl_xor(mx2, off, 16));
    }
    float e1 = __expf(m1 - mx1), e2 = __expf(m2 - mx2);
    float d1 = e1, d2 = e2;
    #pragma unroll
    for (int off = 8; off; off >>= 1) {
        d1 += __shfl_xor(d1, off, 16);
        d2 += __shfl_xor(d2, off, 16);
    }
    float a1 = e1 / d1, a2 = e2 / d2;       // a1[o], a2[o] for o = i

    float cb = a1 * b3[i] + a2 * b1[i];
    #pragma unroll
    for (int off = 8; off; off >>= 1) cb += __shfl_xor(cb, off, 16);

    // v0,v1,v2 for channel i: sum over o via broadcasts of a1/a2
    float v0 = 0.f, v1v = 0.f, v2 = 0.f;
    #pragma unroll
    for (int k = 0; k < CG; ++k) {
        float a1k = __shfl(a1, k, 16);
        float a2k = __shfl(a2, k, 16);
        const float* w = &w3[(k * CG + i) * 3];
        v0  += a1k * w[0];
        v1v += a1k * w[1] + a2k * w1[k * CG + i];
        v2  += a1k * w[2];
    }
    if (lane < 16) {
        float* outv = &vw[g * 64];
        outv[i]      = v0;
        outv[16 + i] = v1v;
        outv[32 + i] = v2;
        if (lane == 0) outv[48] = cb;
    }
}

// ---------------- Pass 3: weights -> sigmoid gate -> output ----------------
// One wave handles one (group, 256-column chunk). Lane t owns columns 4t..4t+3.
__global__ __launch_bounds__(256) void apply_kernel(const float* __restrict__ x,
                                                    const float* __restrict__ vw,
                                                    float* __restrict__ out) {
    int wave = (blockIdx.x * 256 + threadIdx.x) >> 6;   // 0..16383
    int lane = threadIdx.x & 63;
    int g  = wave >> 5;             // 32 chunks per group
    int c0 = (wave & 31) * 256;
    const float* vp = &vw[g * 64];

    const float cb = vp[48];
    float w0 = cb, w1a = cb, w2a = cb, w3a = cb;
    float4 xv[CG];
    #pragma unroll
    for (int i = 0; i < CG; ++i) {
        size_t rb = ((size_t)(g * CG + i)) * LLEN + c0;
        float4 v = *reinterpret_cast<const float4*>(x + rb + 4 * lane);
        xv[i] = v;
        float le = 0.f, re = 0.f;
        if (c0 > 0)            le = x[rb - 1];          // uniform addr -> scalar load
        if (c0 + 256 < LLEN)   re = x[rb + 256];
        float fl = __shfl_up(v.w, 1, 64);
        if (lane == 0)  fl = le;
        float fr = __shfl_down(v.x, 1, 64);
        if (lane == 63) fr = re;
        const float a0 = vp[i], a1 = vp[16 + i], a2 = vp[32 + i];
        w0  += a0 * fl  + a1 * v.x + a2 * v.y;
        w1a += a0 * v.x + a1 * v.y + a2 * v.z;
        w2a += a0 * v.y + a1 * v.z + a2 * v.w;
        w3a += a0 * v.z + a1 * v.w + a2 * fr;
    }
    const float s0 = 1.f / (1.f + __expf(-w0));
    const float s1 = 1.f / (1.f + __expf(-w1a));
    const float s2 = 1.f / (1.f + __expf(-w2a));
    const float s3 = 1.f / (1.f + __expf(-w3a));
    #pragma unroll
    for (int i = 0; i < CG; ++i) {
        size_t rb = ((size_t)(g * CG + i)) * LLEN + c0 + 4 * lane;
        float4 v = xv[i];
        float4 o4 = make_float4(v.x * s0, v.y * s1, v.z * s2, v.w * s3);
        *reinterpret_cast<float4*>(out + rb) = o4;
    }
}

extern "C" void kernel_launch(void* const* d_in, const int* in_sizes, int n_in,
                              void* d_out, int out_size, void* d_ws, size_t ws_size,
                              hipStream_t stream) {
    const float* x  = (const float*)d_in[0];
    const float* w1 = (const float*)d_in[1];
    const float* b1 = (const float*)d_in[2];
    const float* w3 = (const float*)d_in[3];
    const float* b3 = (const float*)d_in[4];
    float* out = (float*)d_out;
    float* S   = (float*)d_ws;              // 8192 floats
    float* vw  = S + NG * CG;               // 512 * 64 floats

    // Pass 1: 8192 rows, 4 waves/block -> 2048 blocks
    rowsum_kernel<<<2048, 256, 0, stream>>>(x, S);
    // Pass 2: one wave per group, 4 groups per block -> 128 blocks
    prep_kernel<<<128, 256, 0, stream>>>(x, S, w1, b1, w3, b3, vw);
    // Pass 3: 512 groups * 32 chunks = 16384 waves / 4 per block = 4096 blocks
    apply_kernel<<<4096, 256, 0, stream>>>(x, vw, out);
}

// Round 4
// 129.040 us; speedup vs baseline: 1.7667x; 1.3904x over previous
//
#include <hip/hip_runtime.h>

#define LLEN 8192
#define CG 16
#define NG 512   // b(16) * GROUPS(32)

typedef float f32x4 __attribute__((ext_vector_type(4)));

// ---------------- Pass 1: row sums + per-group prep, fused. One block per group. ----
// 1024 threads = 16 waves; wave w sums row w. Then wave 0 computes softmax weights
// and the collapsed 3-tap vectors v0,v1,v2 and scalar bias c, writes vw[g*64..].
__global__ __launch_bounds__(1024) void sumprep_kernel(const float* __restrict__ x,
                                                       const float* __restrict__ w1,
                                                       const float* __restrict__ b1,
                                                       const float* __restrict__ w3,
                                                       const float* __restrict__ b3,
                                                       float* __restrict__ vw) {
    int g    = blockIdx.x;              // 0..511
    int wave = threadIdx.x >> 6;        // 0..15  == row within group
    int lane = threadIdx.x & 63;
    __shared__ float S_lds[CG], F_lds[CG], L_lds[CG];

    const float4* xr = reinterpret_cast<const float4*>(x + (size_t)(g * CG + wave) * LLEN);
    float s = 0.f;
    #pragma unroll
    for (int k = 0; k < 32; ++k) {
        float4 v = xr[k * 64 + lane];
        s += (v.x + v.y) + (v.z + v.w);
    }
    #pragma unroll
    for (int off = 32; off; off >>= 1)
        s += __shfl_down(s, off, 64);
    if (lane == 0) S_lds[wave] = s;
    if (threadIdx.x < CG) {
        size_t rb = (size_t)(g * CG + threadIdx.x) * LLEN;
        F_lds[threadIdx.x] = x[rb];
        L_lds[threadIdx.x] = x[rb + (LLEN - 1)];
    }
    __syncthreads();

    if (wave == 0) {
        int i = lane & 15;              // channel index (lanes 16..63 duplicate)
        const float invL = 1.0f / (float)LLEN;
        float s1 = 0.f, s2 = 0.f;
        #pragma unroll
        for (int k = 0; k < CG; ++k) {
            float Sk = S_lds[k], Fk = F_lds[k], Lk = L_lds[k];
            s1 += w1[i * CG + k] * Sk;
            const float* w = &w3[(i * CG + k) * 3];
            s2 += w[0] * (Sk - Lk) + w[1] * Sk + w[2] * (Sk - Fk);
        }
        float m1 = s1 * invL + b1[i];
        float m2 = s2 * invL + b3[i];

        // softmax across the 16-lane group (both heads)
        float mx1 = m1, mx2 = m2;
        #pragma unroll
        for (int off = 8; off; off >>= 1) {
            mx1 = fmaxf(mx1, __shfl_xor(mx1, off, 16));
            mx2 = fmaxf(mx2, __shfl_xor(mx2, off, 16));
        }
        float e1 = __expf(m1 - mx1), e2 = __expf(m2 - mx2);
        float d1 = e1, d2 = e2;
        #pragma unroll
        for (int off = 8; off; off >>= 1) {
            d1 += __shfl_xor(d1, off, 16);
            d2 += __shfl_xor(d2, off, 16);
        }
        float a1 = e1 / d1, a2 = e2 / d2;

        float cb = a1 * b3[i] + a2 * b1[i];
        #pragma unroll
        for (int off = 8; off; off >>= 1) cb += __shfl_xor(cb, off, 16);

        float v0 = 0.f, v1v = 0.f, v2 = 0.f;
        #pragma unroll
        for (int k = 0; k < CG; ++k) {
            float a1k = __shfl(a1, k, 16);
            float a2k = __shfl(a2, k, 16);
            const float* w = &w3[(k * CG + i) * 3];
            v0  += a1k * w[0];
            v1v += a1k * w[1] + a2k * w1[k * CG + i];
            v2  += a1k * w[2];
        }
        if (lane < 16) {
            float* outv = &vw[g * 64];
            outv[i]      = v0;
            outv[16 + i] = v1v;
            outv[32 + i] = v2;
            if (lane == 0) outv[48] = cb;
        }
    }
}

// ---------------- Pass 2: weights -> sigmoid gate -> output ----------------
// One wave handles one (group, 256-column chunk). Lane t owns columns 4t..4t+3.
// Non-temporal stores: keep x resident in L3 so our own write stream doesn't
// evict the lines we're re-reading.
__global__ __launch_bounds__(256) void apply_kernel(const float* __restrict__ x,
                                                    const float* __restrict__ vw,
                                                    float* __restrict__ out) {
    int wave = (blockIdx.x * 256 + threadIdx.x) >> 6;   // 0..16383
    int lane = threadIdx.x & 63;
    int g  = wave >> 5;             // 32 chunks per group
    int c0 = (wave & 31) * 256;
    const float* vp = &vw[g * 64];

    const float cb = vp[48];
    float w0 = cb, w1a = cb, w2a = cb, w3a = cb;
    float4 xv[CG];
    #pragma unroll
    for (int i = 0; i < CG; ++i) {
        size_t rb = ((size_t)(g * CG + i)) * LLEN + c0;
        float4 v = *reinterpret_cast<const float4*>(x + rb + 4 * lane);
        xv[i] = v;
        float le = 0.f, re = 0.f;
        if (c0 > 0)            le = x[rb - 1];          // uniform addr -> scalar load
        if (c0 + 256 < LLEN)   re = x[rb + 256];
        float fl = __shfl_up(v.w, 1, 64);
        if (lane == 0)  fl = le;
        float fr = __shfl_down(v.x, 1, 64);
        if (lane == 63) fr = re;
        const float a0 = vp[i], a1 = vp[16 + i], a2 = vp[32 + i];
        w0  += a0 * fl  + a1 * v.x + a2 * v.y;
        w1a += a0 * v.x + a1 * v.y + a2 * v.z;
        w2a += a0 * v.y + a1 * v.z + a2 * v.w;
        w3a += a0 * v.z + a1 * v.w + a2 * fr;
    }
    const float s0 = 1.f / (1.f + __expf(-w0));
    const float s1 = 1.f / (1.f + __expf(-w1a));
    const float s2 = 1.f / (1.f + __expf(-w2a));
    const float s3 = 1.f / (1.f + __expf(-w3a));
    #pragma unroll
    for (int i = 0; i < CG; ++i) {
        size_t rb = ((size_t)(g * CG + i)) * LLEN + c0 + 4 * lane;
        float4 v = xv[i];
        f32x4 o4 = { v.x * s0, v.y * s1, v.z * s2, v.w * s3 };
        __builtin_nontemporal_store(o4, reinterpret_cast<f32x4*>(out + rb));
    }
}

extern "C" void kernel_launch(void* const* d_in, const int* in_sizes, int n_in,
                              void* d_out, int out_size, void* d_ws, size_t ws_size,
                              hipStream_t stream) {
    const float* x  = (const float*)d_in[0];
    const float* w1 = (const float*)d_in[1];
    const float* b1 = (const float*)d_in[2];
    const float* w3 = (const float*)d_in[3];
    const float* b3 = (const float*)d_in[4];
    float* out = (float*)d_out;
    float* vw  = (float*)d_ws;              // 512 * 64 floats

    // Pass 1: one block per group, 16 waves (one per row), prep fused in-block.
    sumprep_kernel<<<NG, 1024, 0, stream>>>(x, w1, b1, w3, b3, vw);
    // Pass 2: 512 groups * 32 chunks = 16384 waves / 4 per block = 4096 blocks
    apply_kernel<<<4096, 256, 0, stream>>>(x, vw, out);
}